// Round 14
// baseline (207.005 us; speedup 1.0000x reference)
//
#include <hip/hip_runtime.h>
#include <math.h>

#define BB 8
#define LL 2048
#define DD 256

typedef float  f4_t __attribute__((ext_vector_type(4)));
typedef short  s8_t __attribute__((ext_vector_type(8)));

union S8U { s8_t v; unsigned u[4]; };

__device__ __forceinline__ unsigned bitsf(float x){ union{float f; unsigned u;} c; c.f=x; return c.u; }
__device__ __forceinline__ float fbits(unsigned u){ union{float f; unsigned u;} c; c.u=u; return c.f; }
// pack two fp32 -> two bf16 (truncate), elem0 in low half
__device__ __forceinline__ unsigned pkhi(float a, float b){ return (bitsf(a)>>16) | (bitsf(b)&0xffff0000u); }
// pack two fp32 -> two bf16 (round-nearest-ish)
__device__ __forceinline__ unsigned pkrn(float a, float b){
    unsigned ua = bitsf(a) + 0x8000u, ub = bitsf(b) + 0x8000u;
    return (ua>>16) | (ub&0xffff0000u);
}
// single fp32 -> bf16 short (round-nearest-ish)
__device__ __forceinline__ short rnb(float a){ return (short)((bitsf(a) + 0x8000u) >> 16); }

// sigma: row e (0..31) of the key tile -> Vperm slot; makes P's MFMA C/D layout
// directly usable as the PV A-operand (slot k=8q+4a+b holds j=16a+4q+b).
__device__ __forceinline__ int vslot(int e){ return ((e>>2)&3)*8 + ((e>>4)<<2) + (e&3); }

// ---------------- MFMA flash attention — EXACT R13 (95.5 us, verified) ----------------
__global__ __launch_bounds__(512,1)
void attn_kernel(const float* __restrict__ c1, const float* __restrict__ c2,
                 const unsigned char* __restrict__ cmask,
                 float* __restrict__ o0, float* __restrict__ o1,
                 float* __restrict__ mlp,
                 const float* __restrict__ Wf, const float* __restrict__ Wg,
                 unsigned* __restrict__ Whi, unsigned* __restrict__ Wlo,
                 float* __restrict__ gw,
                 int klen, int split, int nattn)
{
    __shared__ short    KhiS[2][32*264];
    __shared__ unsigned VpS [2][256*20];

    // ---- prep path: blocks >= nattn (concurrent with attention blocks) ----
    if ((int)blockIdx.x >= nattn) {
        const int pb  = blockIdx.x - nattn;
        const int ptid = threadIdx.x;
        if (pb == 192) {
            if (ptid < 256) {
#pragma unroll
                for (int i = 0; i < 3; ++i) {
                    float v = (i == 0) ? (Wg[ptid] + Wg[768 + ptid])
                            : (i == 1) ? (Wg[256 + ptid] - Wg[768 + ptid])
                                       :  Wg[512 + ptid];
                    gw[i*256 + ptid] = v;
                }
            }
            return;
        }
        int t    = pb*512 + ptid;                    // [0, 98304)
        int p    = t & 3;
        int lane = (t >> 2) & 63;
        int nt   = (t >> 8) & 15;
        int g2   = t >> 12;                          // kc*3 + seg, [0,24)
        int seg  = g2 % 3;
        int kc   = g2 / 3;
        int kl   = kc*32 + (lane >> 4)*8 + 2*p;
        int n    = nt*16 + (lane & 15);
        float v0, v1;
        if (seg == 0) {
            v0 = Wf[(size_t)kl*DD + n]       + Wf[(size_t)(768 + kl)*DD + n];
            v1 = Wf[(size_t)(kl + 1)*DD + n] + Wf[(size_t)(769 + kl)*DD + n];
        } else if (seg == 1) {
            v0 = Wf[(size_t)(256 + kl)*DD + n] - Wf[(size_t)(768 + kl)*DD + n];
            v1 = Wf[(size_t)(257 + kl)*DD + n] - Wf[(size_t)(769 + kl)*DD + n];
        } else {
            v0 = Wf[(size_t)(512 + kl)*DD + n];
            v1 = Wf[(size_t)(513 + kl)*DD + n];
        }
        Whi[t] = pkhi(v0, v1);
        float l0 = v0 - fbits(bitsf(v0) & 0xffff0000u);
        float l1 = v1 - fbits(bitsf(v1) & 0xffff0000u);
        Wlo[t] = pkrn(l0, l1);
        return;
    }

    const int tid  = threadIdx.x;
    const int lane = tid & 63;
    const int w    = tid >> 6;          // 0..7
    const int il   = lane & 15;
    const int quad = lane >> 4;
    const int col  = tid & 255;         // staging column (d-index)
    const int hr   = (tid >> 8) * 16;   // staging row base (0 or 16)
    const int xv   = (col >> 3) & 3;    // Vp write-swizzle key

    const int blk  = blockIdx.x;
    const int bb   = blk & 7;
    const int qb   = (blk >> 3) & 15;
    const int half = split ? ((blk >> 7) & 1) : 0;
    const int kb   = half * klen;

    float* ob = half ? o1 : o0;

    const float* c1b = c1 + (size_t)bb * LL * DD;
    const float* c2b = c2 + (size_t)bb * LL * DD;
    const unsigned char* mb = cmask + (size_t)bb * LL;

    const int q0w = qb*128 + w*16;      // 16 q-rows per wave

    // Q fragments (hi/lo bf16 split — Q correction kept)
    s8_t qh[8], ql[8];
    {
        const float* qp = c2b + (size_t)(q0w + il)*DD + quad*8;
#pragma unroll
        for (int kd = 0; kd < 8; ++kd) {
            float4 x0 = *(const float4*)(qp + kd*32);
            float4 x1 = *(const float4*)(qp + kd*32 + 4);
            float e[8] = {x0.x,x0.y,x0.z,x0.w,x1.x,x1.y,x1.z,x1.w};
            S8U h, l;
#pragma unroll
            for (int p2 = 0; p2 < 4; ++p2) {
                float a = e[2*p2], b = e[2*p2+1];
                h.u[p2] = pkhi(a, b);
                float alo = a - fbits(bitsf(a)&0xffff0000u);
                float blo = b - fbits(bitsf(b)&0xffff0000u);
                l.u[p2] = pkhi(alo, blo);
            }
            qh[kd] = h.v; ql[kd] = l.v;
        }
    }

    f4_t o[16];
#pragma unroll
    for (int n = 0; n < 16; ++n) o[n] = (f4_t)0.0f;
    float m_s = -INFINITY;
    float l_s = 0.f;

    const int NT = klen >> 5;
    float g[16];

#define STAGE_WRITE(KH, VP) do { \
    _Pragma("unroll") \
    for (int e_ = 0; e_ < 16; ++e_) \
        (KH)[(hr + e_)*264 + col] = rnb(g[e_]); \
    _Pragma("unroll") \
    for (int e_ = 0; e_ < 16; e_ += 2) { \
        const int s_ = vslot(hr + e_) >> 1; \
        (VP)[col*20 + (((s_ >> 2) ^ xv) << 2) + (s_ & 3)] = pkrn(g[e_], g[e_+1]); \
    } \
} while (0)

    // stage tile 0 into buffer 0
#pragma unroll
    for (int e = 0; e < 16; ++e) g[e] = c1b[(size_t)(kb + hr + e)*DD + col];
    STAGE_WRITE(KhiS[0], VpS[0]);
    __syncthreads();

    int cur = 0;
    for (int kt = 0; kt < NT; ++kt) {
        const int k0 = kt << 5;
        if (kt + 1 < NT) {
#pragma unroll
            for (int e = 0; e < 16; ++e)
                g[e] = c1b[(size_t)(kb + k0 + 32 + hr + e)*DD + col];
        }

        const short*    Khi = KhiS[cur];
        const unsigned* Vp  = VpS[cur];

        f4_t acc[2];
        acc[0] = (f4_t)0.0f;
        acc[1] = (f4_t)0.0f;

#pragma unroll
        for (int kd = 0; kd < 8; ++kd) {
            s8_t ah0 = *(const s8_t*)&Khi[(il     )*264 + kd*32 + quad*8];
            s8_t ah1 = *(const s8_t*)&Khi[(16 + il)*264 + kd*32 + quad*8];
            acc[0] = __builtin_amdgcn_mfma_f32_16x16x32_bf16(ah0, qh[kd], acc[0], 0,0,0);
            acc[1] = __builtin_amdgcn_mfma_f32_16x16x32_bf16(ah1, qh[kd], acc[1], 0,0,0);
            acc[0] = __builtin_amdgcn_mfma_f32_16x16x32_bf16(ah0, ql[kd], acc[0], 0,0,0);
            acc[1] = __builtin_amdgcn_mfma_f32_16x16x32_bf16(ah1, ql[kd], acc[1], 0,0,0);
        }

        unsigned mu[2];
#pragma unroll
        for (int mj = 0; mj < 2; ++mj)
            mu[mj] = *(const unsigned*)(mb + kb + k0 + 16*mj + 4*quad);

        // online softmax (defer-max THR=0)
        const int ig = q0w + il;
        float tm = -INFINITY;           // this tile's max
        f4_t p[2];
#pragma unroll
        for (int mj = 0; mj < 2; ++mj) {
#pragma unroll
            for (int b = 0; b < 4; ++b) {
                int jg = kb + k0 + 16*mj + 4*quad + b;
                float s = acc[mj][b];
                bool dead = (((mu[mj] >> (8*b)) & 0xff) != 0) || (jg == ig);
                s = dead ? -INFINITY : s;
                p[mj][b] = s;
                tm = fmaxf(tm, s);
            }
        }
        tm = fmaxf(tm, __shfl_xor(tm, 16, 64));
        tm = fmaxf(tm, __shfl_xor(tm, 32, 64));
        const bool stable = __all(tm <= m_s);   // wave-uniform
        const float mn = stable ? m_s : fmaxf(m_s, tm);
        float rs = 0.f;
#pragma unroll
        for (int mj = 0; mj < 2; ++mj) {
#pragma unroll
            for (int b = 0; b < 4; ++b) {
                float pe = __expf(p[mj][b] - mn);
                p[mj][b] = pe;
                rs += pe;
            }
        }
        rs += __shfl_xor(rs, 16, 64);
        rs += __shfl_xor(rs, 32, 64);
        if (!stable) {
            float al = __expf(m_s - mn);
            l_s = l_s*al + rs;
            m_s = mn;
            float am[4];
#pragma unroll
            for (int b = 0; b < 4; ++b) am[b] = __shfl(al, 4*quad + b, 64);
#pragma unroll
            for (int n = 0; n < 16; ++n) {
#pragma unroll
                for (int b = 0; b < 4; ++b) o[n][b] *= am[b];
            }
        } else {
            l_s += rs;
        }

        // pack P -> bf16 A-fragment
        s8_t ap;
        {
            S8U a;
            a.u[0] = pkrn(p[0][0], p[0][1]);
            a.u[1] = pkrn(p[0][2], p[0][3]);
            a.u[2] = pkrn(p[1][0], p[1][1]);
            a.u[3] = pkrn(p[1][2], p[1][3]);
            ap = a.v;
        }
#pragma unroll
        for (int n = 0; n < 16; ++n) {
            const int vr = 16*n + il;
            s8_t bv = *(const s8_t*)(Vp + vr*20 + ((quad ^ ((vr >> 3) & 3)) << 2));
            o[n] = __builtin_amdgcn_mfma_f32_16x16x32_bf16(ap, bv, o[n], 0,0,0);
        }

        // stage next tile into the other buffer
        if (kt + 1 < NT) {
            short*    KhiN = KhiS[cur^1];
            unsigned* VpN  = VpS[cur^1];
            STAGE_WRITE(KhiN, VpN);
        }
        __syncthreads();
        cur ^= 1;
    }
#undef STAGE_WRITE

    const int rbq = bb*LL + q0w;
    if (split) {
        const int rbase = rbq + 4*quad;
#pragma unroll
        for (int n = 0; n < 16; ++n) {
            const int d = 16*n + il;
#pragma unroll
            for (int b = 0; b < 4; ++b)
                ob[(size_t)(rbase + b)*DD + d] = o[n][b];
        }
        if (lane < 16) {
            int r = rbq + lane;
            *(float2*)(&mlp[((size_t)half*16384 + r)*2]) = make_float2(m_s, l_s);
        }
    } else {
        float invl[4];
#pragma unroll
        for (int b = 0; b < 4; ++b) invl[b] = 1.0f / __shfl(l_s, 4*quad + b, 64);
        const int rbase = rbq + 4*quad;
#pragma unroll
        for (int n = 0; n < 16; ++n) {
            const int d = 16*n + il;
#pragma unroll
            for (int b = 0; b < 4; ++b)
                ob[(size_t)(rbase + b)*DD + d] = o[n][b] * invl[b];
        }
    }
}

// ---------------- z-prep — R10's FCONV extracted, writing fragment-major zG + gate ----------------
// One pass chip-wide (was once per fusion block). 512 blocks x 256 thr; block
// covers 32 rows; thread (sr = tid>>3, cg = tid&7) handles 4 cols per kc slice.
// Values/order identical to R10/R13's FCONV -> bitwise-identical fragments & gate.
__global__ __launch_bounds__(256)
void zprep_kernel(const float* __restrict__ c2,
                  const float* __restrict__ P0, const float* __restrict__ P1,
                  const float* __restrict__ mlp, const float* __restrict__ gw,
                  const float* __restrict__ bg,
                  unsigned* __restrict__ zG, float* __restrict__ gv, int ns)
{
    __shared__ float gwL[768];
    __shared__ float gpart[32][8];

    const int tid = threadIdx.x;
    const int sr  = tid >> 3;           // 0..31
    const int cg  = tid & 7;            // 0..7 (4 cols each)
    const size_t row = (size_t)blockIdx.x * 32 + sr;
    const int rb   = (int)(row >> 6);
    const int mt   = (int)((row >> 4) & 3);
    const int il   = (int)(row & 15);
    const int quad = cg >> 1;
    const int lane = quad*16 + il;
    const int hf   = cg & 1;            // which 2-uint half of the lane's 4 uints

    const float* c2r = c2 + row*DD;
    const float* p0r = P0 + row*DD;
    const float* p1r = P1 + row*DD;

    for (int i = tid; i < 768; i += 256) gwL[i] = gw[i];

    float ca0 = 1.f, ca1 = 0.f;
    if (ns == 2) {
        float m0 = mlp[row*2],             l0 = mlp[row*2 + 1];
        float m1 = mlp[(16384 + row)*2],   l1 = mlp[(16384 + row)*2 + 1];
        float M  = fmaxf(m0, m1);
        float a0 = __expf(m0 - M), a1 = __expf(m1 - M);
        float inv = 1.0f / (a0*l0 + a1*l1);
        ca0 = a0*inv; ca1 = a1*inv;
    }
    __syncthreads();

    float gatep = 0.f;
#pragma unroll
    for (int kc = 0; kc < 8; ++kc) {
        const int co = kc*32 + cg*4;
        float4 pr4 = *(const float4*)(c2r + co);
        f4_t   u4  = *(const f4_t*)(p0r + co);
        if (ns == 2) {
            f4_t v4 = *(const f4_t*)(p1r + co);
            u4 = u4*ca0 + v4*ca1;
        }
        float ea0 = pr4.x, ea1 = pr4.y, ea2 = pr4.z, ea3 = pr4.w;
        float d0 = ea0*u4[0], d1 = ea1*u4[1], d2 = ea2*u4[2], d3 = ea3*u4[3];
        gatep += ea0*gwL[co+0] + u4[0]*gwL[256+co+0] + d0*gwL[512+co+0]
               + ea1*gwL[co+1] + u4[1]*gwL[256+co+1] + d1*gwL[512+co+1]
               + ea2*gwL[co+2] + u4[2]*gwL[256+co+2] + d2*gwL[512+co+2]
               + ea3*gwL[co+3] + u4[3]*gwL[256+co+3] + d3*gwL[512+co+3];
        // fragment-major: zi(rb,kc,seg,mt,lane) = (((rb*8+kc)*3+seg)*4+mt)*64+lane (x4 uints)
        const size_t base = ((((size_t)(rb*8 + kc)*3 + 0)*4 + mt)*64 + lane)*4 + hf*2;
        *(uint2*)&zG[base       ] = make_uint2(pkrn(ea0, ea1), pkrn(ea2, ea3));
        *(uint2*)&zG[base + 1024] = make_uint2(pkrn(u4[0], u4[1]), pkrn(u4[2], u4[3]));
        *(uint2*)&zG[base + 2048] = make_uint2(pkrn(d0, d1), pkrn(d2, d3));
    }
    gpart[sr][cg] = gatep;
    __syncthreads();
    if (tid < 32) {
        float s = 0.f;
#pragma unroll
        for (int c = 0; c < 8; ++c) s += gpart[tid][c];
        gv[(size_t)blockIdx.x*32 + tid] = 1.0f / (1.0f + __expf(-(s + bg[0])));
    }
}

// ---------------- fusion GEMM — no LDS, no barriers, all-fragment global reads ----------------
// Grid 512 = (rb 0..255) x (ch 0..1); wave ntg = ch*8 + w (R9/R12-proven mapping).
// z-frags + weight-frags both fragment-major -> every wave load is 1 KB coalesced.
// Accumulation order identical to R13 -> bitwise-identical output.
__global__ __launch_bounds__(512,1)
void fusion_gemm(const float* __restrict__ c2, const unsigned* __restrict__ zG,
                 const unsigned* __restrict__ Whi, const unsigned* __restrict__ Wlo,
                 const float* __restrict__ gv, const float* __restrict__ bf,
                 float* __restrict__ out)
{
    const int tid  = threadIdx.x;
    const int lane = tid & 63;
    const int w    = tid >> 6;          // 0..7
    const int il   = lane & 15;
    const int quad = lane >> 4;
    const int rb   = blockIdx.x & 255;
    const int ch   = blockIdx.x >> 8;
    const size_t row0 = (size_t)rb * 64;
    const int ntg  = ch*8 + w;

    f4_t acc[4];
#pragma unroll
    for (int mt = 0; mt < 4; ++mt) acc[mt] = (f4_t)0.0f;

    for (int kc = 0; kc < 8; ++kc) {
        s8_t fa[4], fb[4], fc[4];
#pragma unroll
        for (int mt = 0; mt < 4; ++mt) {
            const size_t zi = ((((size_t)(rb*8 + kc)*3 + 0)*4 + mt)*64 + lane)*4;
            fa[mt] = *(const s8_t*)&zG[zi];
            fb[mt] = *(const s8_t*)&zG[zi + 1024];
            fc[mt] = *(const s8_t*)&zG[zi + 2048];
        }
        const size_t f0 = ((size_t)((kc*3 + 0)*16 + ntg)*64 + lane)*4;
        const size_t f1 = ((size_t)((kc*3 + 1)*16 + ntg)*64 + lane)*4;
        const size_t f2 = ((size_t)((kc*3 + 2)*16 + ntg)*64 + lane)*4;
        s8_t w0h = *(const s8_t*)(Whi + f0), w0l = *(const s8_t*)(Wlo + f0);
        s8_t w1h = *(const s8_t*)(Whi + f1), w1l = *(const s8_t*)(Wlo + f1);
        s8_t w2h = *(const s8_t*)(Whi + f2), w2l = *(const s8_t*)(Wlo + f2);
#pragma unroll
        for (int mt = 0; mt < 4; ++mt) {
            acc[mt] = __builtin_amdgcn_mfma_f32_16x16x32_bf16(fa[mt], w0h, acc[mt], 0,0,0);
            acc[mt] = __builtin_amdgcn_mfma_f32_16x16x32_bf16(fa[mt], w0l, acc[mt], 0,0,0);
            acc[mt] = __builtin_amdgcn_mfma_f32_16x16x32_bf16(fb[mt], w1h, acc[mt], 0,0,0);
            acc[mt] = __builtin_amdgcn_mfma_f32_16x16x32_bf16(fb[mt], w1l, acc[mt], 0,0,0);
            acc[mt] = __builtin_amdgcn_mfma_f32_16x16x32_bf16(fc[mt], w2h, acc[mt], 0,0,0);
            acc[mt] = __builtin_amdgcn_mfma_f32_16x16x32_bf16(fc[mt], w2l, acc[mt], 0,0,0);
        }
    }

    // epilogue: row = 16mt + 4quad + b, col = ntg*16 + il
    const int col = ch*128 + w*16 + il;
    const float bfv = bf[col];
#pragma unroll
    for (int mt = 0; mt < 4; ++mt) {
#pragma unroll
        for (int b = 0; b < 4; ++b) {
            const int r = 16*mt + 4*quad + b;
            const float g = gv[row0 + r];
            const float cc = c2[(row0 + r)*DD + col];
            out[(row0 + r)*DD + col] = g * tanhf(acc[mt][b] + bfv) + (1.f - g) * cc;
        }
    }
}

// ---------------- MFMA fusion — R11-exact (fallback path only) ----------------
__global__ __launch_bounds__(512,1)
void fusion_mfma(const float* __restrict__ c2,
                 const float* __restrict__ P0, const float* __restrict__ P1,
                 const float* __restrict__ mlp,
                 const unsigned* __restrict__ Whi, const unsigned* __restrict__ Wlo,
                 const float* __restrict__ gw, const float* __restrict__ bg,
                 const float* __restrict__ bf, float* __restrict__ out, int ns)
{
    __shared__ float    gwL[768];
    __shared__ unsigned zA[2][64*20];
    __shared__ unsigned zB[2][64*20];
    __shared__ unsigned zC[2][64*20];
    __shared__ float    gpart[64][8];
    __shared__ float    gv[64];

    const int tid  = threadIdx.x;
    const int lane = tid & 63;
    const int w    = tid >> 6;
    const int il   = lane & 15;
    const int quad = lane >> 4;
    const int srow = tid >> 3;
    const int scg  = tid & 7;
    const size_t row0 = (size_t)blockIdx.x * 64;

    const float* c2b = c2 + row0*DD;
    const float* P0b = P0 + row0*DD;
    const float* P1b = P1 + row0*DD;

    for (int i = tid; i < 768; i += 512) gwL[i] = gw[i];

    float ca0 = 1.f, ca1 = 0.f;
    if (ns == 2) {
        const size_t r = row0 + srow;
        float m0 = mlp[r*2],             l0 = mlp[r*2 + 1];
        float m1 = mlp[(16384 + r)*2],   l1 = mlp[(16384 + r)*2 + 1];
        float M  = fmaxf(m0, m1);
        float a0 = __expf(m0 - M), a1 = __expf(m1 - M);
        float inv = 1.0f / (a0*l0 + a1*l1);
        ca0 = a0*inv; ca1 = a1*inv;
    }
    __syncthreads();

    float gatep = 0.f;
    float4 pr4; f4_t u4;

#define FLOAD(kc_) do { \
    const int off_ = srow*DD + (kc_)*32 + scg*4; \
    pr4 = *(const float4*)(c2b + off_); \
    u4  = *(const f4_t*)(P0b + off_); \
    if (ns == 2) { \
        f4_t v4_ = *(const f4_t*)(P1b + off_); \
        u4 = u4*ca0 + v4_*ca1; \
    } \
} while (0)

#define FCONV(buf_, kc_) do { \
    const int co_ = (kc_)*32 + scg*4; \
    float ea0_ = pr4.x, ea1_ = pr4.y, ea2_ = pr4.z, ea3_ = pr4.w; \
    float d0_ = ea0_*u4[0], d1_ = ea1_*u4[1], d2_ = ea2_*u4[2], d3_ = ea3_*u4[3]; \
    gatep += ea0_*gwL[co_+0] + u4[0]*gwL[256+co_+0] + d0_*gwL[512+co_+0] \
           + ea1_*gwL[co_+1] + u4[1]*gwL[256+co_+1] + d1_*gwL[512+co_+1] \
           + ea2_*gwL[co_+2] + u4[2]*gwL[256+co_+2] + d2_*gwL[512+co_+2] \
           + ea3_*gwL[co_+3] + u4[3]*gwL[256+co_+3] + d3_*gwL[512+co_+3]; \
    const int zi_ = srow*20 + scg*2; \
    *(uint2*)&zA[buf_][zi_] = make_uint2(pkrn(ea0_, ea1_), pkrn(ea2_, ea3_)); \
    *(uint2*)&zB[buf_][zi_] = make_uint2(pkrn(u4[0], u4[1]), pkrn(u4[2], u4[3])); \
    *(uint2*)&zC[buf_][zi_] = make_uint2(pkrn(d0_, d1_),   pkrn(d2_, d3_)); \
} while (0)

    f4_t acc[4][2];
#pragma unroll
    for (int mt = 0; mt < 4; ++mt)
#pragma unroll
        for (int nt = 0; nt < 2; ++nt) acc[mt][nt] = (f4_t)0.0f;

    FLOAD(0); FCONV(0, 0);
    __syncthreads();

    int cur = 0;
    for (int kc = 0; kc < 8; ++kc) {
        if (kc + 1 < 8) FLOAD(kc + 1);

        s8_t fa[4], fb[4], fc[4];
#pragma unroll
        for (int mt = 0; mt < 4; ++mt) {
            const int fi = (16*mt + il)*20 + quad*4;
            fa[mt] = *(const s8_t*)&zA[cur][fi];
            fb[mt] = *(const s8_t*)&zB[cur][fi];
            fc[mt] = *(const s8_t*)&zC[cur][fi];
        }
#pragma unroll
        for (int nt = 0; nt < 2; ++nt) {
            const int ntg = w*2 + nt;
            const size_t f0 = ((size_t)((kc*3 + 0)*16 + ntg)*64 + lane)*4;
            const size_t f1 = ((size_t)((kc*3 + 1)*16 + ntg)*64 + lane)*4;
            const size_t f2 = ((size_t)((kc*3 + 2)*16 + ntg)*64 + lane)*4;
            s8_t w0h = *(const s8_t*)(Whi + f0), w0l = *(const s8_t*)(Wlo + f0);
            s8_t w1h = *(const s8_t*)(Whi + f1), w1l = *(const s8_t*)(Wlo + f1);
            s8_t w2h = *(const s8_t*)(Whi + f2), w2l = *(const s8_t*)(Wlo + f2);
#pragma unroll
            for (int mt = 0; mt < 4; ++mt) {
                acc[mt][nt] = __builtin_amdgcn_mfma_f32_16x16x32_bf16(fa[mt], w0h, acc[mt][nt], 0,0,0);
                acc[mt][nt] = __builtin_amdgcn_mfma_f32_16x16x32_bf16(fa[mt], w0l, acc[mt][nt], 0,0,0);
                acc[mt][nt] = __builtin_amdgcn_mfma_f32_16x16x32_bf16(fb[mt], w1h, acc[mt][nt], 0,0,0);
                acc[mt][nt] = __builtin_amdgcn_mfma_f32_16x16x32_bf16(fb[mt], w1l, acc[mt][nt], 0,0,0);
                acc[mt][nt] = __builtin_amdgcn_mfma_f32_16x16x32_bf16(fc[mt], w2h, acc[mt][nt], 0,0,0);
                acc[mt][nt] = __builtin_amdgcn_mfma_f32_16x16x32_bf16(fc[mt], w2l, acc[mt][nt], 0,0,0);
            }
        }

        if (kc + 1 < 8) FCONV(cur ^ 1, kc + 1);
        __syncthreads();
        cur ^= 1;
    }
#undef FLOAD
#undef FCONV

    gpart[srow][scg] = gatep;
    __syncthreads();
    if (tid < 64) {
        float s = 0.f;
#pragma unroll
        for (int cg = 0; cg < 8; ++cg) s += gpart[tid][cg];
        gv[tid] = 1.0f / (1.0f + __expf(-(s + bg[0])));
    }
    __syncthreads();

#pragma unroll
    for (int nt = 0; nt < 2; ++nt) {
        const int col = w*32 + nt*16 + il;
        const float bfv = bf[col];
#pragma unroll
        for (int mt = 0; mt < 4; ++mt) {
#pragma unroll
            for (int b = 0; b < 4; ++b) {
                const int r = 16*mt + 4*quad + b;
                const float g = gv[r];
                const float cc = c2b[(size_t)r*DD + col];
                out[(row0 + r)*DD + col] = g * tanhf(acc[mt][nt][b] + bfv) + (1.f - g) * cc;
            }
        }
    }
}

extern "C" void kernel_launch(void* const* d_in, const int* in_sizes, int n_in,
                              void* d_out, int out_size, void* d_ws, size_t ws_size,
                              hipStream_t stream)
{
    const float* c1 = (const float*)d_in[0];
    const float* c2 = (const float*)d_in[1];
    const unsigned char* cmask = (const unsigned char*)d_in[2];
    const float* Wf = (const float*)d_in[3];
    const float* bf = (const float*)d_in[4];
    const float* Wg = (const float*)d_in[5];
    const float* bg = (const float*)d_in[6];

    const size_t aug_elems  = (size_t)16384 * 256;   // 4,194,304 floats
    const size_t frag_elems = (size_t)98304;         // uints per Whi/Wlo buffer
    const size_t ml2_elems  = (size_t)2 * 16384 * 2; // 65,536 floats
    const size_t z_elems    = (size_t)6291456;       // uints (25.2 MB)

    // New layout: Op0 | mlp | Whi | Wlo | gw | zG | gv ; Op1 = d_out (dead until gemm).
    const size_t need_new = (aug_elems + ml2_elems + 2*frag_elems + 768
                             + z_elems + 16384) * sizeof(float);  // 43,060,224 B

    float* wsf = (float*)d_ws;

    if (ws_size >= need_new) {
        float*    Op0 = wsf;
        float*    mlp = wsf + aug_elems;
        unsigned* Whi = (unsigned*)(mlp + ml2_elems);
        unsigned* Wlo = Whi + frag_elems;
        float*    gw  = (float*)(Wlo + frag_elems);
        unsigned* zG  = (unsigned*)(gw + 768);
        float*    gvp = (float*)(zG + z_elems);
        float*    Op1 = (float*)d_out;     // scratch until fusion_gemm writes it

        attn_kernel<<<dim3(449), dim3(512), 0, stream>>>(c1, c2, cmask,
                                                         Op0, Op1, mlp,
                                                         Wf, Wg, Whi, Wlo, gw,
                                                         1024, 1, 256);
        zprep_kernel<<<dim3(512), dim3(256), 0, stream>>>(c2, Op0, Op1, mlp,
                                                          gw, bg, zG, gvp, 2);
        fusion_gemm<<<dim3(512), dim3(512), 0, stream>>>(c2, zG, Whi, Wlo,
                                                         gvp, bf, (float*)d_out);
    } else {
        // ---- no-split fallback (R13-exact): attn normalizes in-kernel; R11 fusion ns==1 ----
        float* aug = wsf;
        unsigned* Whi = (unsigned*)(wsf + aug_elems);
        unsigned* Wlo = Whi + frag_elems;
        float*    gw  = (float*)(Wlo + frag_elems);

        attn_kernel<<<dim3(321), dim3(512), 0, stream>>>(c1, c2, cmask,
                                                         aug, aug, wsf,
                                                         Wf, Wg, Whi, Wlo, gw,
                                                         2048, 0, 128);
        fusion_mfma<<<dim3(256), dim3(512), 0, stream>>>(c2, aug, aug, wsf,
                                                         Whi, Wlo, gw, bg, bf,
                                                         (float*)d_out, 1);
    }
}

// Round 15
// 199.460 us; speedup vs baseline: 1.0378x; 1.0378x over previous
//
#include <hip/hip_runtime.h>
#include <math.h>

#define BB 8
#define LL 2048
#define DD 256

typedef float  f4_t __attribute__((ext_vector_type(4)));
typedef short  s8_t __attribute__((ext_vector_type(8)));

union S8U { s8_t v; unsigned u[4]; };

__device__ __forceinline__ unsigned bitsf(float x){ union{float f; unsigned u;} c; c.f=x; return c.u; }
__device__ __forceinline__ float fbits(unsigned u){ union{float f; unsigned u;} c; c.u=u; return c.f; }
// pack two fp32 -> two bf16 (truncate), elem0 in low half
__device__ __forceinline__ unsigned pkhi(float a, float b){ return (bitsf(a)>>16) | (bitsf(b)&0xffff0000u); }
// pack two fp32 -> two bf16 (round-nearest-ish)
__device__ __forceinline__ unsigned pkrn(float a, float b){
    unsigned ua = bitsf(a) + 0x8000u, ub = bitsf(b) + 0x8000u;
    return (ua>>16) | (ub&0xffff0000u);
}
// single fp32 -> bf16 short (round-nearest-ish)
__device__ __forceinline__ short rnb(float a){ return (short)((bitsf(a) + 0x8000u) >> 16); }

// sigma: row e (0..31) of the key tile -> Vperm slot; makes P's MFMA C/D layout
// directly usable as the PV A-operand (slot k=8q+4a+b holds j=16a+4q+b).
__device__ __forceinline__ int vslot(int e){ return ((e>>2)&3)*8 + ((e>>4)<<2) + (e&3); }

// ---------------- MFMA flash attention — R15: R13 minus Q-lo correction ----------------
// R11 precedent: dropping K's lo-correction (round-nearest pack) added exactly the
// predicted ~0.023 zero-mean noise (0.0156 -> 0.0391) and cut QK work. Q's lo term
// is the symmetric correction on the same pathway: drop it too (Q packed pkrn).
// QK = 2 MFMA/kd (was 4); per wave-tile MFMA 48 -> 32 (-33%); ql[8] (32 VGPR) freed.
// Expected absmax ~ 0.0156 + sqrt(2)*0.023 ~ 0.048 vs threshold 0.0719.
// Everything else (Vp swizzle, defer-max, dbuf, absorbed W-prep) identical to R13.
__global__ __launch_bounds__(512,1)
void attn_kernel(const float* __restrict__ c1, const float* __restrict__ c2,
                 const unsigned char* __restrict__ cmask,
                 float* __restrict__ o0, float* __restrict__ o1,
                 float* __restrict__ mlp,
                 const float* __restrict__ Wf, const float* __restrict__ Wg,
                 unsigned* __restrict__ Whi, unsigned* __restrict__ Wlo,
                 float* __restrict__ gw,
                 int klen, int split, int nattn)
{
    __shared__ short    KhiS[2][32*264];
    __shared__ unsigned VpS [2][256*20];

    // ---- prep path: blocks >= nattn (concurrent with attention blocks) ----
    if ((int)blockIdx.x >= nattn) {
        const int pb  = blockIdx.x - nattn;
        const int ptid = threadIdx.x;
        if (pb == 192) {
            if (ptid < 256) {
#pragma unroll
                for (int i = 0; i < 3; ++i) {
                    float v = (i == 0) ? (Wg[ptid] + Wg[768 + ptid])
                            : (i == 1) ? (Wg[256 + ptid] - Wg[768 + ptid])
                                       :  Wg[512 + ptid];
                    gw[i*256 + ptid] = v;
                }
            }
            return;
        }
        int t    = pb*512 + ptid;                    // [0, 98304)
        int p    = t & 3;
        int lane = (t >> 2) & 63;
        int nt   = (t >> 8) & 15;
        int g2   = t >> 12;                          // kc*3 + seg, [0,24)
        int seg  = g2 % 3;
        int kc   = g2 / 3;
        int kl   = kc*32 + (lane >> 4)*8 + 2*p;
        int n    = nt*16 + (lane & 15);
        float v0, v1;
        if (seg == 0) {
            v0 = Wf[(size_t)kl*DD + n]       + Wf[(size_t)(768 + kl)*DD + n];
            v1 = Wf[(size_t)(kl + 1)*DD + n] + Wf[(size_t)(769 + kl)*DD + n];
        } else if (seg == 1) {
            v0 = Wf[(size_t)(256 + kl)*DD + n] - Wf[(size_t)(768 + kl)*DD + n];
            v1 = Wf[(size_t)(257 + kl)*DD + n] - Wf[(size_t)(769 + kl)*DD + n];
        } else {
            v0 = Wf[(size_t)(512 + kl)*DD + n];
            v1 = Wf[(size_t)(513 + kl)*DD + n];
        }
        Whi[t] = pkhi(v0, v1);
        float l0 = v0 - fbits(bitsf(v0) & 0xffff0000u);
        float l1 = v1 - fbits(bitsf(v1) & 0xffff0000u);
        Wlo[t] = pkrn(l0, l1);
        return;
    }

    const int tid  = threadIdx.x;
    const int lane = tid & 63;
    const int w    = tid >> 6;          // 0..7
    const int il   = lane & 15;
    const int quad = lane >> 4;
    const int col  = tid & 255;         // staging column (d-index)
    const int hr   = (tid >> 8) * 16;   // staging row base (0 or 16)
    const int xv   = (col >> 3) & 3;    // Vp write-swizzle key

    const int blk  = blockIdx.x;
    const int bb   = blk & 7;
    const int qb   = (blk >> 3) & 15;
    const int half = split ? ((blk >> 7) & 1) : 0;
    const int kb   = half * klen;

    float* ob = half ? o1 : o0;

    const float* c1b = c1 + (size_t)bb * LL * DD;
    const float* c2b = c2 + (size_t)bb * LL * DD;
    const unsigned char* mb = cmask + (size_t)bb * LL;

    const int q0w = qb*128 + w*16;      // 16 q-rows per wave

    // Q fragments — single bf16, round-nearest (lo-correction dropped, R15)
    s8_t qh[8];
    {
        const float* qp = c2b + (size_t)(q0w + il)*DD + quad*8;
#pragma unroll
        for (int kd = 0; kd < 8; ++kd) {
            float4 x0 = *(const float4*)(qp + kd*32);
            float4 x1 = *(const float4*)(qp + kd*32 + 4);
            S8U h;
            h.u[0] = pkrn(x0.x, x0.y);
            h.u[1] = pkrn(x0.z, x0.w);
            h.u[2] = pkrn(x1.x, x1.y);
            h.u[3] = pkrn(x1.z, x1.w);
            qh[kd] = h.v;
        }
    }

    f4_t o[16];
#pragma unroll
    for (int n = 0; n < 16; ++n) o[n] = (f4_t)0.0f;
    float m_s = -INFINITY;
    float l_s = 0.f;

    const int NT = klen >> 5;
    float g[16];

#define STAGE_WRITE(KH, VP) do { \
    _Pragma("unroll") \
    for (int e_ = 0; e_ < 16; ++e_) \
        (KH)[(hr + e_)*264 + col] = rnb(g[e_]); \
    _Pragma("unroll") \
    for (int e_ = 0; e_ < 16; e_ += 2) { \
        const int s_ = vslot(hr + e_) >> 1; \
        (VP)[col*20 + (((s_ >> 2) ^ xv) << 2) + (s_ & 3)] = pkrn(g[e_], g[e_+1]); \
    } \
} while (0)

    // stage tile 0 into buffer 0
#pragma unroll
    for (int e = 0; e < 16; ++e) g[e] = c1b[(size_t)(kb + hr + e)*DD + col];
    STAGE_WRITE(KhiS[0], VpS[0]);
    __syncthreads();

    int cur = 0;
    for (int kt = 0; kt < NT; ++kt) {
        const int k0 = kt << 5;
        if (kt + 1 < NT) {
#pragma unroll
            for (int e = 0; e < 16; ++e)
                g[e] = c1b[(size_t)(kb + k0 + 32 + hr + e)*DD + col];
        }

        const short*    Khi = KhiS[cur];
        const unsigned* Vp  = VpS[cur];

        f4_t acc[2];
        acc[0] = (f4_t)0.0f;
        acc[1] = (f4_t)0.0f;

#pragma unroll
        for (int kd = 0; kd < 8; ++kd) {
            s8_t ah0 = *(const s8_t*)&Khi[(il     )*264 + kd*32 + quad*8];
            s8_t ah1 = *(const s8_t*)&Khi[(16 + il)*264 + kd*32 + quad*8];
            acc[0] = __builtin_amdgcn_mfma_f32_16x16x32_bf16(ah0, qh[kd], acc[0], 0,0,0);
            acc[1] = __builtin_amdgcn_mfma_f32_16x16x32_bf16(ah1, qh[kd], acc[1], 0,0,0);
        }

        unsigned mu[2];
#pragma unroll
        for (int mj = 0; mj < 2; ++mj)
            mu[mj] = *(const unsigned*)(mb + kb + k0 + 16*mj + 4*quad);

        // online softmax (defer-max THR=0)
        const int ig = q0w + il;
        float tm = -INFINITY;           // this tile's max
        f4_t p[2];
#pragma unroll
        for (int mj = 0; mj < 2; ++mj) {
#pragma unroll
            for (int b = 0; b < 4; ++b) {
                int jg = kb + k0 + 16*mj + 4*quad + b;
                float s = acc[mj][b];
                bool dead = (((mu[mj] >> (8*b)) & 0xff) != 0) || (jg == ig);
                s = dead ? -INFINITY : s;
                p[mj][b] = s;
                tm = fmaxf(tm, s);
            }
        }
        tm = fmaxf(tm, __shfl_xor(tm, 16, 64));
        tm = fmaxf(tm, __shfl_xor(tm, 32, 64));
        const bool stable = __all(tm <= m_s);   // wave-uniform
        const float mn = stable ? m_s : fmaxf(m_s, tm);
        float rs = 0.f;
#pragma unroll
        for (int mj = 0; mj < 2; ++mj) {
#pragma unroll
            for (int b = 0; b < 4; ++b) {
                float pe = __expf(p[mj][b] - mn);
                p[mj][b] = pe;
                rs += pe;
            }
        }
        rs += __shfl_xor(rs, 16, 64);
        rs += __shfl_xor(rs, 32, 64);
        if (!stable) {
            float al = __expf(m_s - mn);
            l_s = l_s*al + rs;
            m_s = mn;
            float am[4];
#pragma unroll
            for (int b = 0; b < 4; ++b) am[b] = __shfl(al, 4*quad + b, 64);
#pragma unroll
            for (int n = 0; n < 16; ++n) {
#pragma unroll
                for (int b = 0; b < 4; ++b) o[n][b] *= am[b];
            }
        } else {
            l_s += rs;
        }

        // pack P -> bf16 A-fragment
        s8_t ap;
        {
            S8U a;
            a.u[0] = pkrn(p[0][0], p[0][1]);
            a.u[1] = pkrn(p[0][2], p[0][3]);
            a.u[2] = pkrn(p[1][0], p[1][1]);
            a.u[3] = pkrn(p[1][2], p[1][3]);
            ap = a.v;
        }
#pragma unroll
        for (int n = 0; n < 16; ++n) {
            const int vr = 16*n + il;
            s8_t bv = *(const s8_t*)(Vp + vr*20 + ((quad ^ ((vr >> 3) & 3)) << 2));
            o[n] = __builtin_amdgcn_mfma_f32_16x16x32_bf16(ap, bv, o[n], 0,0,0);
        }

        // stage next tile into the other buffer
        if (kt + 1 < NT) {
            short*    KhiN = KhiS[cur^1];
            unsigned* VpN  = VpS[cur^1];
            STAGE_WRITE(KhiN, VpN);
        }
        __syncthreads();
        cur ^= 1;
    }
#undef STAGE_WRITE

    const int rbq = bb*LL + q0w;
    if (split) {
        const int rbase = rbq + 4*quad;
#pragma unroll
        for (int n = 0; n < 16; ++n) {
            const int d = 16*n + il;
#pragma unroll
            for (int b = 0; b < 4; ++b)
                ob[(size_t)(rbase + b)*DD + d] = o[n][b];
        }
        if (lane < 16) {
            int r = rbq + lane;
            *(float2*)(&mlp[((size_t)half*16384 + r)*2]) = make_float2(m_s, l_s);
        }
    } else {
        float invl[4];
#pragma unroll
        for (int b = 0; b < 4; ++b) invl[b] = 1.0f / __shfl(l_s, 4*quad + b, 64);
        const int rbase = rbq + 4*quad;
#pragma unroll
        for (int n = 0; n < 16; ++n) {
            const int d = 16*n + il;
#pragma unroll
            for (int b = 0; b < 4; ++b)
                ob[(size_t)(rbase + b)*DD + d] = o[n][b] * invl[b];
        }
    }
}

// ---------------- MFMA fusion — R11/R13-exact (coop LDS z-staging, grid 256) ----------------
__global__ __launch_bounds__(512,1)
void fusion_mfma(const float* __restrict__ c2,
                 const float* __restrict__ P0, const float* __restrict__ P1,
                 const float* __restrict__ mlp,
                 const unsigned* __restrict__ Whi, const unsigned* __restrict__ Wlo,
                 const float* __restrict__ gw, const float* __restrict__ bg,
                 const float* __restrict__ bf, float* __restrict__ out, int ns)
{
    __shared__ float    gwL[768];
    __shared__ unsigned zA[2][64*20];   // 64 rows x 20 uints (40 bf16, 32 used)
    __shared__ unsigned zB[2][64*20];
    __shared__ unsigned zC[2][64*20];
    __shared__ float    gpart[64][8];
    __shared__ float    gv[64];

    const int tid  = threadIdx.x;
    const int lane = tid & 63;
    const int w    = tid >> 6;          // 0..7
    const int il   = lane & 15;
    const int quad = lane >> 4;
    const int srow = tid >> 3;          // 0..63  staging row
    const int scg  = tid & 7;           // 0..7   staging col-group (4 cols)
    const size_t row0 = (size_t)blockIdx.x * 64;

    const float* c2b = c2 + row0*DD;
    const float* P0b = P0 + row0*DD;
    const float* P1b = P1 + row0*DD;

    for (int i = tid; i < 768; i += 512) gwL[i] = gw[i];

    // combine factors for this thread's staging row
    float ca0 = 1.f, ca1 = 0.f;
    if (ns == 2) {
        const size_t r = row0 + srow;
        float m0 = mlp[r*2],             l0 = mlp[r*2 + 1];
        float m1 = mlp[(16384 + r)*2],   l1 = mlp[(16384 + r)*2 + 1];
        float M  = fmaxf(m0, m1);
        float a0 = __expf(m0 - M), a1 = __expf(m1 - M);
        float inv = 1.0f / (a0*l0 + a1*l1);
        ca0 = a0*inv; ca1 = a1*inv;
    }
    __syncthreads();   // gwL visible to all before first gate FMAs

    float gatep = 0.f;
    float4 pr4; f4_t u4;

#define FLOAD(kc_) do { \
    const int off_ = srow*DD + (kc_)*32 + scg*4; \
    pr4 = *(const float4*)(c2b + off_); \
    u4  = *(const f4_t*)(P0b + off_); \
    if (ns == 2) { \
        f4_t v4_ = *(const f4_t*)(P1b + off_); \
        u4 = u4*ca0 + v4_*ca1; \
    } \
} while (0)

#define FCONV(buf_, kc_) do { \
    const int co_ = (kc_)*32 + scg*4; \
    float ea0_ = pr4.x, ea1_ = pr4.y, ea2_ = pr4.z, ea3_ = pr4.w; \
    float d0_ = ea0_*u4[0], d1_ = ea1_*u4[1], d2_ = ea2_*u4[2], d3_ = ea3_*u4[3]; \
    gatep += ea0_*gwL[co_+0] + u4[0]*gwL[256+co_+0] + d0_*gwL[512+co_+0] \
           + ea1_*gwL[co_+1] + u4[1]*gwL[256+co_+1] + d1_*gwL[512+co_+1] \
           + ea2_*gwL[co_+2] + u4[2]*gwL[256+co_+2] + d2_*gwL[512+co_+2] \
           + ea3_*gwL[co_+3] + u4[3]*gwL[256+co_+3] + d3_*gwL[512+co_+3]; \
    const int zi_ = srow*20 + scg*2; \
    *(uint2*)&zA[buf_][zi_] = make_uint2(pkrn(ea0_, ea1_), pkrn(ea2_, ea3_)); \
    *(uint2*)&zB[buf_][zi_] = make_uint2(pkrn(u4[0], u4[1]), pkrn(u4[2], u4[3])); \
    *(uint2*)&zC[buf_][zi_] = make_uint2(pkrn(d0_, d1_),   pkrn(d2_, d3_)); \
} while (0)

    f4_t acc[4][2];
#pragma unroll
    for (int mt = 0; mt < 4; ++mt)
#pragma unroll
        for (int nt = 0; nt < 2; ++nt) acc[mt][nt] = (f4_t)0.0f;

    FLOAD(0); FCONV(0, 0);
    __syncthreads();

    int cur = 0;
    for (int kc = 0; kc < 8; ++kc) {
        if (kc + 1 < 8) FLOAD(kc + 1);      // issue global loads early

        s8_t fa[4], fb[4], fc[4];
#pragma unroll
        for (int mt = 0; mt < 4; ++mt) {
            const int fi = (16*mt + il)*20 + quad*4;
            fa[mt] = *(const s8_t*)&zA[cur][fi];
            fb[mt] = *(const s8_t*)&zB[cur][fi];
            fc[mt] = *(const s8_t*)&zC[cur][fi];
        }
#pragma unroll
        for (int nt = 0; nt < 2; ++nt) {
            const int ntg = w*2 + nt;       // 0..15
            const size_t f0 = ((size_t)((kc*3 + 0)*16 + ntg)*64 + lane)*4;
            const size_t f1 = ((size_t)((kc*3 + 1)*16 + ntg)*64 + lane)*4;
            const size_t f2 = ((size_t)((kc*3 + 2)*16 + ntg)*64 + lane)*4;
            s8_t w0h = *(const s8_t*)(Whi + f0), w0l = *(const s8_t*)(Wlo + f0);
            s8_t w1h = *(const s8_t*)(Whi + f1), w1l = *(const s8_t*)(Wlo + f1);
            s8_t w2h = *(const s8_t*)(Whi + f2), w2l = *(const s8_t*)(Wlo + f2);
#pragma unroll
            for (int mt = 0; mt < 4; ++mt) {
                acc[mt][nt] = __builtin_amdgcn_mfma_f32_16x16x32_bf16(fa[mt], w0h, acc[mt][nt], 0,0,0);
                acc[mt][nt] = __builtin_amdgcn_mfma_f32_16x16x32_bf16(fa[mt], w0l, acc[mt][nt], 0,0,0);
                acc[mt][nt] = __builtin_amdgcn_mfma_f32_16x16x32_bf16(fb[mt], w1h, acc[mt][nt], 0,0,0);
                acc[mt][nt] = __builtin_amdgcn_mfma_f32_16x16x32_bf16(fb[mt], w1l, acc[mt][nt], 0,0,0);
                acc[mt][nt] = __builtin_amdgcn_mfma_f32_16x16x32_bf16(fc[mt], w2h, acc[mt][nt], 0,0,0);
                acc[mt][nt] = __builtin_amdgcn_mfma_f32_16x16x32_bf16(fc[mt], w2l, acc[mt][nt], 0,0,0);
            }
        }

        if (kc + 1 < 8) FCONV(cur ^ 1, kc + 1);
        __syncthreads();
        cur ^= 1;
    }
#undef FLOAD
#undef FCONV

    // cooperative gate reduce: per-thread partial -> LDS -> 64-thread finish
    gpart[srow][scg] = gatep;
    __syncthreads();
    if (tid < 64) {
        float s = 0.f;
#pragma unroll
        for (int cg = 0; cg < 8; ++cg) s += gpart[tid][cg];
        gv[tid] = 1.0f / (1.0f + __expf(-(s + bg[0])));
    }
    __syncthreads();

    // epilogue: row = 16mt + 4quad + b, col = 32w + 16nt + il
#pragma unroll
    for (int nt = 0; nt < 2; ++nt) {
        const int col = w*32 + nt*16 + il;
        const float bfv = bf[col];
#pragma unroll
        for (int mt = 0; mt < 4; ++mt) {
#pragma unroll
            for (int b = 0; b < 4; ++b) {
                const int r = 16*mt + 4*quad + b;
                const float g = gv[r];
                const float cc = c2b[(size_t)r*DD + col];
                out[(row0 + r)*DD + col] = g * tanhf(acc[mt][nt][b] + bfv) + (1.f - g) * cc;
            }
        }
    }
}

extern "C" void kernel_launch(void* const* d_in, const int* in_sizes, int n_in,
                              void* d_out, int out_size, void* d_ws, size_t ws_size,
                              hipStream_t stream)
{
    const float* c1 = (const float*)d_in[0];
    const float* c2 = (const float*)d_in[1];
    const unsigned char* cmask = (const unsigned char*)d_in[2];
    const float* Wf = (const float*)d_in[3];
    const float* bf = (const float*)d_in[4];
    const float* Wg = (const float*)d_in[5];
    const float* bg = (const float*)d_in[6];

    const size_t aug_elems   = (size_t)16384 * 256;      // 4,194,304 floats
    const size_t frag_elems  = (size_t)98304;            // uints per Whi/Wlo buffer

    // Layout: Op0 | Op1 | mlp2 | Wfrag(Whi,Wlo,gw).
    const size_t ml2_elems = (size_t)2 * 16384 * 2;
    const size_t need2     = (2*aug_elems + ml2_elems + aug_elems) * sizeof(float); // 50,593,792 B gate

    float* wsf = (float*)d_ws;

    if (ws_size >= need2) {
        float* Op0 = wsf;
        float* Op1 = wsf + aug_elems;
        float* mlp = wsf + 2*aug_elems;
        unsigned* Whi = (unsigned*)(wsf + 2*aug_elems + ml2_elems);
        unsigned* Wlo = Whi + frag_elems;
        float*    gw  = (float*)(Wlo + frag_elems);

        // attn (256 blocks) + embedded prep (193 blocks) in one dispatch
        attn_kernel<<<dim3(449), dim3(512), 0, stream>>>(c1, c2, cmask,
                                                         Op0, Op1, mlp,
                                                         Wf, Wg, Whi, Wlo, gw,
                                                         1024, 1, 256);
        fusion_mfma<<<dim3(256), dim3(512), 0, stream>>>(c2, Op0, Op1, mlp,
                                                         Whi, Wlo, gw, bg, bf,
                                                         (float*)d_out, 2);
    } else {
        // ---- no-split fallback: attn normalizes in-kernel; fusion ns==1 ----
        float* aug = wsf;
        unsigned* Whi = (unsigned*)(wsf + aug_elems);
        unsigned* Wlo = Whi + frag_elems;
        float*    gw  = (float*)(Wlo + frag_elems);

        attn_kernel<<<dim3(321), dim3(512), 0, stream>>>(c1, c2, cmask,
                                                         aug, aug, wsf,
                                                         Wf, Wg, Whi, Wlo, gw,
                                                         2048, 0, 128);
        fusion_mfma<<<dim3(256), dim3(512), 0, stream>>>(c2, aug, aug, wsf,
                                                         Whi, Wlo, gw, bg, bf,
                                                         (float*)d_out, 1);
    }
}

// Round 16
// 198.192 us; speedup vs baseline: 1.0445x; 1.0064x over previous
//
#include <hip/hip_runtime.h>
#include <math.h>

#define BB 8
#define LL 2048
#define DD 256

typedef float  f4_t __attribute__((ext_vector_type(4)));
typedef short  s8_t __attribute__((ext_vector_type(8)));

union S8U { s8_t v; unsigned u[4]; };

__device__ __forceinline__ unsigned bitsf(float x){ union{float f; unsigned u;} c; c.f=x; return c.u; }
__device__ __forceinline__ float fbits(unsigned u){ union{float f; unsigned u;} c; c.u=u; return c.f; }
// pack two fp32 -> two bf16 (truncate), elem0 in low half
__device__ __forceinline__ unsigned pkhi(float a, float b){ return (bitsf(a)>>16) | (bitsf(b)&0xffff0000u); }
// pack two fp32 -> two bf16 (round-nearest-ish)
__device__ __forceinline__ unsigned pkrn(float a, float b){
    unsigned ua = bitsf(a) + 0x8000u, ub = bitsf(b) + 0x8000u;
    return (ua>>16) | (ub&0xffff0000u);
}
// single fp32 -> bf16 short (round-nearest-ish)
__device__ __forceinline__ short rnb(float a){ return (short)((bitsf(a) + 0x8000u) >> 16); }

// sigma: row e (0..31) of the key tile -> Vperm slot; makes P's MFMA C/D layout
// directly usable as the PV A-operand (slot k=8q+4a+b holds j=16a+4q+b).
__device__ __forceinline__ int vslot(int e){ return ((e>>2)&3)*8 + ((e>>4)<<2) + (e&3); }

// ---------------- MFMA flash attention — EXACT R15 (93-95 us, verified) ----------------
__global__ __launch_bounds__(512,1)
void attn_kernel(const float* __restrict__ c1, const float* __restrict__ c2,
                 const unsigned char* __restrict__ cmask,
                 float* __restrict__ o0, float* __restrict__ o1,
                 float* __restrict__ mlp,
                 const float* __restrict__ Wf, const float* __restrict__ Wg,
                 unsigned* __restrict__ Whi, unsigned* __restrict__ Wlo,
                 float* __restrict__ gw,
                 int klen, int split, int nattn)
{
    __shared__ short    KhiS[2][32*264];
    __shared__ unsigned VpS [2][256*20];

    // ---- prep path: blocks >= nattn (concurrent with attention blocks) ----
    if ((int)blockIdx.x >= nattn) {
        const int pb  = blockIdx.x - nattn;
        const int ptid = threadIdx.x;
        if (pb == 192) {
            if (ptid < 256) {
#pragma unroll
                for (int i = 0; i < 3; ++i) {
                    float v = (i == 0) ? (Wg[ptid] + Wg[768 + ptid])
                            : (i == 1) ? (Wg[256 + ptid] - Wg[768 + ptid])
                                       :  Wg[512 + ptid];
                    gw[i*256 + ptid] = v;
                }
            }
            return;
        }
        int t    = pb*512 + ptid;                    // [0, 98304)
        int p    = t & 3;
        int lane = (t >> 2) & 63;
        int nt   = (t >> 8) & 15;
        int g2   = t >> 12;                          // kc*3 + seg, [0,24)
        int seg  = g2 % 3;
        int kc   = g2 / 3;
        int kl   = kc*32 + (lane >> 4)*8 + 2*p;
        int n    = nt*16 + (lane & 15);
        float v0, v1;
        if (seg == 0) {
            v0 = Wf[(size_t)kl*DD + n]       + Wf[(size_t)(768 + kl)*DD + n];
            v1 = Wf[(size_t)(kl + 1)*DD + n] + Wf[(size_t)(769 + kl)*DD + n];
        } else if (seg == 1) {
            v0 = Wf[(size_t)(256 + kl)*DD + n] - Wf[(size_t)(768 + kl)*DD + n];
            v1 = Wf[(size_t)(257 + kl)*DD + n] - Wf[(size_t)(769 + kl)*DD + n];
        } else {
            v0 = Wf[(size_t)(512 + kl)*DD + n];
            v1 = Wf[(size_t)(513 + kl)*DD + n];
        }
        Whi[t] = pkhi(v0, v1);
        float l0 = v0 - fbits(bitsf(v0) & 0xffff0000u);
        float l1 = v1 - fbits(bitsf(v1) & 0xffff0000u);
        Wlo[t] = pkrn(l0, l1);
        return;
    }

    const int tid  = threadIdx.x;
    const int lane = tid & 63;
    const int w    = tid >> 6;          // 0..7
    const int il   = lane & 15;
    const int quad = lane >> 4;
    const int col  = tid & 255;         // staging column (d-index)
    const int hr   = (tid >> 8) * 16;   // staging row base (0 or 16)
    const int xv   = (col >> 3) & 3;    // Vp write-swizzle key

    const int blk  = blockIdx.x;
    const int bb   = blk & 7;
    const int qb   = (blk >> 3) & 15;
    const int half = split ? ((blk >> 7) & 1) : 0;
    const int kb   = half * klen;

    float* ob = half ? o1 : o0;

    const float* c1b = c1 + (size_t)bb * LL * DD;
    const float* c2b = c2 + (size_t)bb * LL * DD;
    const unsigned char* mb = cmask + (size_t)bb * LL;

    const int q0w = qb*128 + w*16;      // 16 q-rows per wave

    // Q fragments — single bf16, round-nearest (lo-correction dropped, R15)
    s8_t qh[8];
    {
        const float* qp = c2b + (size_t)(q0w + il)*DD + quad*8;
#pragma unroll
        for (int kd = 0; kd < 8; ++kd) {
            float4 x0 = *(const float4*)(qp + kd*32);
            float4 x1 = *(const float4*)(qp + kd*32 + 4);
            S8U h;
            h.u[0] = pkrn(x0.x, x0.y);
            h.u[1] = pkrn(x0.z, x0.w);
            h.u[2] = pkrn(x1.x, x1.y);
            h.u[3] = pkrn(x1.z, x1.w);
            qh[kd] = h.v;
        }
    }

    f4_t o[16];
#pragma unroll
    for (int n = 0; n < 16; ++n) o[n] = (f4_t)0.0f;
    float m_s = -INFINITY;
    float l_s = 0.f;

    const int NT = klen >> 5;
    float g[16];

#define STAGE_WRITE(KH, VP) do { \
    _Pragma("unroll") \
    for (int e_ = 0; e_ < 16; ++e_) \
        (KH)[(hr + e_)*264 + col] = rnb(g[e_]); \
    _Pragma("unroll") \
    for (int e_ = 0; e_ < 16; e_ += 2) { \
        const int s_ = vslot(hr + e_) >> 1; \
        (VP)[col*20 + (((s_ >> 2) ^ xv) << 2) + (s_ & 3)] = pkrn(g[e_], g[e_+1]); \
    } \
} while (0)

    // stage tile 0 into buffer 0
#pragma unroll
    for (int e = 0; e < 16; ++e) g[e] = c1b[(size_t)(kb + hr + e)*DD + col];
    STAGE_WRITE(KhiS[0], VpS[0]);
    __syncthreads();

    int cur = 0;
    for (int kt = 0; kt < NT; ++kt) {
        const int k0 = kt << 5;
        if (kt + 1 < NT) {
#pragma unroll
            for (int e = 0; e < 16; ++e)
                g[e] = c1b[(size_t)(kb + k0 + 32 + hr + e)*DD + col];
        }

        const short*    Khi = KhiS[cur];
        const unsigned* Vp  = VpS[cur];

        f4_t acc[2];
        acc[0] = (f4_t)0.0f;
        acc[1] = (f4_t)0.0f;

#pragma unroll
        for (int kd = 0; kd < 8; ++kd) {
            s8_t ah0 = *(const s8_t*)&Khi[(il     )*264 + kd*32 + quad*8];
            s8_t ah1 = *(const s8_t*)&Khi[(16 + il)*264 + kd*32 + quad*8];
            acc[0] = __builtin_amdgcn_mfma_f32_16x16x32_bf16(ah0, qh[kd], acc[0], 0,0,0);
            acc[1] = __builtin_amdgcn_mfma_f32_16x16x32_bf16(ah1, qh[kd], acc[1], 0,0,0);
        }

        unsigned mu[2];
#pragma unroll
        for (int mj = 0; mj < 2; ++mj)
            mu[mj] = *(const unsigned*)(mb + kb + k0 + 16*mj + 4*quad);

        // online softmax (defer-max THR=0)
        const int ig = q0w + il;
        float tm = -INFINITY;           // this tile's max
        f4_t p[2];
#pragma unroll
        for (int mj = 0; mj < 2; ++mj) {
#pragma unroll
            for (int b = 0; b < 4; ++b) {
                int jg = kb + k0 + 16*mj + 4*quad + b;
                float s = acc[mj][b];
                bool dead = (((mu[mj] >> (8*b)) & 0xff) != 0) || (jg == ig);
                s = dead ? -INFINITY : s;
                p[mj][b] = s;
                tm = fmaxf(tm, s);
            }
        }
        tm = fmaxf(tm, __shfl_xor(tm, 16, 64));
        tm = fmaxf(tm, __shfl_xor(tm, 32, 64));
        const bool stable = __all(tm <= m_s);   // wave-uniform
        const float mn = stable ? m_s : fmaxf(m_s, tm);
        float rs = 0.f;
#pragma unroll
        for (int mj = 0; mj < 2; ++mj) {
#pragma unroll
            for (int b = 0; b < 4; ++b) {
                float pe = __expf(p[mj][b] - mn);
                p[mj][b] = pe;
                rs += pe;
            }
        }
        rs += __shfl_xor(rs, 16, 64);
        rs += __shfl_xor(rs, 32, 64);
        if (!stable) {
            float al = __expf(m_s - mn);
            l_s = l_s*al + rs;
            m_s = mn;
            float am[4];
#pragma unroll
            for (int b = 0; b < 4; ++b) am[b] = __shfl(al, 4*quad + b, 64);
#pragma unroll
            for (int n = 0; n < 16; ++n) {
#pragma unroll
                for (int b = 0; b < 4; ++b) o[n][b] *= am[b];
            }
        } else {
            l_s += rs;
        }

        // pack P -> bf16 A-fragment
        s8_t ap;
        {
            S8U a;
            a.u[0] = pkrn(p[0][0], p[0][1]);
            a.u[1] = pkrn(p[0][2], p[0][3]);
            a.u[2] = pkrn(p[1][0], p[1][1]);
            a.u[3] = pkrn(p[1][2], p[1][3]);
            ap = a.v;
        }
#pragma unroll
        for (int n = 0; n < 16; ++n) {
            const int vr = 16*n + il;
            s8_t bv = *(const s8_t*)(Vp + vr*20 + ((quad ^ ((vr >> 3) & 3)) << 2));
            o[n] = __builtin_amdgcn_mfma_f32_16x16x32_bf16(ap, bv, o[n], 0,0,0);
        }

        // stage next tile into the other buffer
        if (kt + 1 < NT) {
            short*    KhiN = KhiS[cur^1];
            unsigned* VpN  = VpS[cur^1];
            STAGE_WRITE(KhiN, VpN);
        }
        __syncthreads();
        cur ^= 1;
    }
#undef STAGE_WRITE

    const int rbq = bb*LL + q0w;
    if (split) {
        const int rbase = rbq + 4*quad;
#pragma unroll
        for (int n = 0; n < 16; ++n) {
            const int d = 16*n + il;
#pragma unroll
            for (int b = 0; b < 4; ++b)
                ob[(size_t)(rbase + b)*DD + d] = o[n][b];
        }
        if (lane < 16) {
            int r = rbq + lane;
            *(float2*)(&mlp[((size_t)half*16384 + r)*2]) = make_float2(m_s, l_s);
        }
    } else {
        float invl[4];
#pragma unroll
        for (int b = 0; b < 4; ++b) invl[b] = 1.0f / __shfl(l_s, 4*quad + b, 64);
        const int rbase = rbq + 4*quad;
#pragma unroll
        for (int n = 0; n < 16; ++n) {
            const int d = 16*n + il;
#pragma unroll
            for (int b = 0; b < 4; ++b)
                ob[(size_t)(rbase + b)*DD + d] = o[n][b] * invl[b];
        }
    }
}

// ---------------- MFMA fusion — R16: R15 + per-kc weight-fragment prefetch ----------------
// R15 flag: fusion's per-kc weight loads (12 x 1KB global, L2-resident) sit inside
// the dependent chain (barrier -> loads -> MFMA); __syncthreads per kc blocks
// compiler hoisting. Double-buffer the weight frags (wA/wB, 96 VGPR) and issue
// kc+1's loads right after FLOAD(kc+1), before this kc's MFMA block. kc loop
// fully unrolled so the ping-pong index is compile-time (no scratch, rule #20).
// Pure load reordering: output bitwise identical to R15.
__global__ __launch_bounds__(512,1)
void fusion_mfma(const float* __restrict__ c2,
                 const float* __restrict__ P0, const float* __restrict__ P1,
                 const float* __restrict__ mlp,
                 const unsigned* __restrict__ Whi, const unsigned* __restrict__ Wlo,
                 const float* __restrict__ gw, const float* __restrict__ bg,
                 const float* __restrict__ bf, float* __restrict__ out, int ns)
{
    __shared__ float    gwL[768];
    __shared__ unsigned zA[2][64*20];   // 64 rows x 20 uints (40 bf16, 32 used)
    __shared__ unsigned zB[2][64*20];
    __shared__ unsigned zC[2][64*20];
    __shared__ float    gpart[64][8];
    __shared__ float    gv[64];

    const int tid  = threadIdx.x;
    const int lane = tid & 63;
    const int w    = tid >> 6;          // 0..7
    const int il   = lane & 15;
    const int quad = lane >> 4;
    const int srow = tid >> 3;          // 0..63  staging row
    const int scg  = tid & 7;           // 0..7   staging col-group (4 cols)
    const size_t row0 = (size_t)blockIdx.x * 64;

    const float* c2b = c2 + row0*DD;
    const float* P0b = P0 + row0*DD;
    const float* P1b = P1 + row0*DD;

    for (int i = tid; i < 768; i += 512) gwL[i] = gw[i];

    // combine factors for this thread's staging row
    float ca0 = 1.f, ca1 = 0.f;
    if (ns == 2) {
        const size_t r = row0 + srow;
        float m0 = mlp[r*2],             l0 = mlp[r*2 + 1];
        float m1 = mlp[(16384 + r)*2],   l1 = mlp[(16384 + r)*2 + 1];
        float M  = fmaxf(m0, m1);
        float a0 = __expf(m0 - M), a1 = __expf(m1 - M);
        float inv = 1.0f / (a0*l0 + a1*l1);
        ca0 = a0*inv; ca1 = a1*inv;
    }
    __syncthreads();   // gwL visible to all before first gate FMAs

    float gatep = 0.f;
    float4 pr4; f4_t u4;

#define FLOAD(kc_) do { \
    const int off_ = srow*DD + (kc_)*32 + scg*4; \
    pr4 = *(const float4*)(c2b + off_); \
    u4  = *(const f4_t*)(P0b + off_); \
    if (ns == 2) { \
        f4_t v4_ = *(const f4_t*)(P1b + off_); \
        u4 = u4*ca0 + v4_*ca1; \
    } \
} while (0)

#define FCONV(buf_, kc_) do { \
    const int co_ = (kc_)*32 + scg*4; \
    float ea0_ = pr4.x, ea1_ = pr4.y, ea2_ = pr4.z, ea3_ = pr4.w; \
    float d0_ = ea0_*u4[0], d1_ = ea1_*u4[1], d2_ = ea2_*u4[2], d3_ = ea3_*u4[3]; \
    gatep += ea0_*gwL[co_+0] + u4[0]*gwL[256+co_+0] + d0_*gwL[512+co_+0] \
           + ea1_*gwL[co_+1] + u4[1]*gwL[256+co_+1] + d1_*gwL[512+co_+1] \
           + ea2_*gwL[co_+2] + u4[2]*gwL[256+co_+2] + d2_*gwL[512+co_+2] \
           + ea3_*gwL[co_+3] + u4[3]*gwL[256+co_+3] + d3_*gwL[512+co_+3]; \
    const int zi_ = srow*20 + scg*2; \
    *(uint2*)&zA[buf_][zi_] = make_uint2(pkrn(ea0_, ea1_), pkrn(ea2_, ea3_)); \
    *(uint2*)&zB[buf_][zi_] = make_uint2(pkrn(u4[0], u4[1]), pkrn(u4[2], u4[3])); \
    *(uint2*)&zC[buf_][zi_] = make_uint2(pkrn(d0_, d1_),   pkrn(d2_, d3_)); \
} while (0)

// load the 12 weight fragments (2 ntg x {w0h,w0l,w1h,w1l,w2h,w2l}) for kc_ into WB
#define LOADW(kc_, WB) do { \
    _Pragma("unroll") \
    for (int nt_ = 0; nt_ < 2; ++nt_) { \
        const int ntg_ = w*2 + nt_; \
        const size_t f0_ = ((size_t)(((kc_)*3 + 0)*16 + ntg_)*64 + lane)*4; \
        const size_t f1_ = ((size_t)(((kc_)*3 + 1)*16 + ntg_)*64 + lane)*4; \
        const size_t f2_ = ((size_t)(((kc_)*3 + 2)*16 + ntg_)*64 + lane)*4; \
        WB[nt_][0] = *(const s8_t*)(Whi + f0_); WB[nt_][1] = *(const s8_t*)(Wlo + f0_); \
        WB[nt_][2] = *(const s8_t*)(Whi + f1_); WB[nt_][3] = *(const s8_t*)(Wlo + f1_); \
        WB[nt_][4] = *(const s8_t*)(Whi + f2_); WB[nt_][5] = *(const s8_t*)(Wlo + f2_); \
    } \
} while (0)

    f4_t acc[4][2];
#pragma unroll
    for (int mt = 0; mt < 4; ++mt)
#pragma unroll
        for (int nt = 0; nt < 2; ++nt) acc[mt][nt] = (f4_t)0.0f;

    s8_t wA[2][6], wB[2][6];
    LOADW(0, wA);
    FLOAD(0); FCONV(0, 0);
    __syncthreads();

    int cur = 0;
#pragma unroll
    for (int kc = 0; kc < 8; ++kc) {
        if (kc + 1 < 8) {
            FLOAD(kc + 1);              // issue z global loads early
            if (kc & 1) LOADW(kc + 1, wA); else LOADW(kc + 1, wB);  // prefetch weights
        }

        // read this kc's fragments from LDS
        s8_t fa[4], fb[4], fc[4];
#pragma unroll
        for (int mt = 0; mt < 4; ++mt) {
            const int fi = (16*mt + il)*20 + quad*4;
            fa[mt] = *(const s8_t*)&zA[cur][fi];
            fb[mt] = *(const s8_t*)&zB[cur][fi];
            fc[mt] = *(const s8_t*)&zC[cur][fi];
        }
#pragma unroll
        for (int nt = 0; nt < 2; ++nt) {
#pragma unroll
            for (int mt = 0; mt < 4; ++mt) {
                if (kc & 1) {
                    acc[mt][nt] = __builtin_amdgcn_mfma_f32_16x16x32_bf16(fa[mt], wB[nt][0], acc[mt][nt], 0,0,0);
                    acc[mt][nt] = __builtin_amdgcn_mfma_f32_16x16x32_bf16(fa[mt], wB[nt][1], acc[mt][nt], 0,0,0);
                    acc[mt][nt] = __builtin_amdgcn_mfma_f32_16x16x32_bf16(fb[mt], wB[nt][2], acc[mt][nt], 0,0,0);
                    acc[mt][nt] = __builtin_amdgcn_mfma_f32_16x16x32_bf16(fb[mt], wB[nt][3], acc[mt][nt], 0,0,0);
                    acc[mt][nt] = __builtin_amdgcn_mfma_f32_16x16x32_bf16(fc[mt], wB[nt][4], acc[mt][nt], 0,0,0);
                    acc[mt][nt] = __builtin_amdgcn_mfma_f32_16x16x32_bf16(fc[mt], wB[nt][5], acc[mt][nt], 0,0,0);
                } else {
                    acc[mt][nt] = __builtin_amdgcn_mfma_f32_16x16x32_bf16(fa[mt], wA[nt][0], acc[mt][nt], 0,0,0);
                    acc[mt][nt] = __builtin_amdgcn_mfma_f32_16x16x32_bf16(fa[mt], wA[nt][1], acc[mt][nt], 0,0,0);
                    acc[mt][nt] = __builtin_amdgcn_mfma_f32_16x16x32_bf16(fb[mt], wA[nt][2], acc[mt][nt], 0,0,0);
                    acc[mt][nt] = __builtin_amdgcn_mfma_f32_16x16x32_bf16(fb[mt], wA[nt][3], acc[mt][nt], 0,0,0);
                    acc[mt][nt] = __builtin_amdgcn_mfma_f32_16x16x32_bf16(fc[mt], wA[nt][4], acc[mt][nt], 0,0,0);
                    acc[mt][nt] = __builtin_amdgcn_mfma_f32_16x16x32_bf16(fc[mt], wA[nt][5], acc[mt][nt], 0,0,0);
                }
            }
        }

        // stage kc+1 into the other buffer
        if (kc + 1 < 8) FCONV(cur ^ 1, kc + 1);
        __syncthreads();
        cur ^= 1;
    }
#undef FLOAD
#undef FCONV
#undef LOADW

    // cooperative gate reduce: per-thread partial -> LDS -> 64-thread finish
    gpart[srow][scg] = gatep;
    __syncthreads();
    if (tid < 64) {
        float s = 0.f;
#pragma unroll
        for (int cg = 0; cg < 8; ++cg) s += gpart[tid][cg];
        gv[tid] = 1.0f / (1.0f + __expf(-(s + bg[0])));
    }
    __syncthreads();

    // epilogue: row = 16mt + 4quad + b, col = 32w + 16nt + il
#pragma unroll
    for (int nt = 0; nt < 2; ++nt) {
        const int col = w*32 + nt*16 + il;
        const float bfv = bf[col];
#pragma unroll
        for (int mt = 0; mt < 4; ++mt) {
#pragma unroll
            for (int b = 0; b < 4; ++b) {
                const int r = 16*mt + 4*quad + b;
                const float g = gv[r];
                const float cc = c2b[(size_t)r*DD + col];
                out[(row0 + r)*DD + col] = g * tanhf(acc[mt][nt][b] + bfv) + (1.f - g) * cc;
            }
        }
    }
}

extern "C" void kernel_launch(void* const* d_in, const int* in_sizes, int n_in,
                              void* d_out, int out_size, void* d_ws, size_t ws_size,
                              hipStream_t stream)
{
    const float* c1 = (const float*)d_in[0];
    const float* c2 = (const float*)d_in[1];
    const unsigned char* cmask = (const unsigned char*)d_in[2];
    const float* Wf = (const float*)d_in[3];
    const float* bf = (const float*)d_in[4];
    const float* Wg = (const float*)d_in[5];
    const float* bg = (const float*)d_in[6];

    const size_t aug_elems   = (size_t)16384 * 256;      // 4,194,304 floats
    const size_t frag_elems  = (size_t)98304;            // uints per Whi/Wlo buffer

    // Layout: Op0 | Op1 | mlp2 | Wfrag(Whi,Wlo,gw).
    const size_t ml2_elems = (size_t)2 * 16384 * 2;
    const size_t need2     = (2*aug_elems + ml2_elems + aug_elems) * sizeof(float); // 50,593,792 B gate

    float* wsf = (float*)d_ws;

    if (ws_size >= need2) {
        float* Op0 = wsf;
        float* Op1 = wsf + aug_elems;
        float* mlp = wsf + 2*aug_elems;
        unsigned* Whi = (unsigned*)(wsf + 2*aug_elems + ml2_elems);
        unsigned* Wlo = Whi + frag_elems;
        float*    gw  = (float*)(Wlo + frag_elems);

        // attn (256 blocks) + embedded prep (193 blocks) in one dispatch
        attn_kernel<<<dim3(449), dim3(512), 0, stream>>>(c1, c2, cmask,
                                                         Op0, Op1, mlp,
                                                         Wf, Wg, Whi, Wlo, gw,
                                                         1024, 1, 256);
        fusion_mfma<<<dim3(256), dim3(512), 0, stream>>>(c2, Op0, Op1, mlp,
                                                         Whi, Wlo, gw, bg, bf,
                                                         (float*)d_out, 2);
    } else {
        // ---- no-split fallback: attn normalizes in-kernel; fusion ns==1 ----
        float* aug = wsf;
        unsigned* Whi = (unsigned*)(wsf + aug_elems);
        unsigned* Wlo = Whi + frag_elems;
        float*    gw  = (float*)(Wlo + frag_elems);

        attn_kernel<<<dim3(321), dim3(512), 0, stream>>>(c1, c2, cmask,
                                                         aug, aug, wsf,
                                                         Wf, Wg, Whi, Wlo, gw,
                                                         2048, 0, 128);
        fusion_mfma<<<dim3(256), dim3(512), 0, stream>>>(c2, aug, aug, wsf,
                                                         Whi, Wlo, gw, bg, bf,
                                                         (float*)d_out, 1);
    }
}